// Round 16
// baseline (345.304 us; speedup 1.0000x reference)
//
#include <hip/hip_runtime.h>
#include <hip/hip_bf16.h>

#define N_NODES 50000
#define N_EDGES 400000
#define DIM_IN  128
#define DIM_H   192
#define N_LAYERS 3
#define BN_EPSF 1e-5f
#define SCAN_NBLK 49  // ceil(50000/1024)
#define INV_N (1.f / N_NODES)
#define NSHADOW 8
#define SSTRIDE 384   // per-shadow: [0..191]=sum, [192..383]=sumsq
#define WTP_BLOCKS 138  // ceil((7*24*192 + 16*192)/256)

typedef __attribute__((ext_vector_type(8))) short short8;
typedef __attribute__((ext_vector_type(4))) float floatx4;

union FragU { uint4 u; short8 s; };

__device__ __forceinline__ float relu_f(float x) { return x > 0.f ? x : 0.f; }
__device__ __forceinline__ unsigned short f2bf(float x) {
  __hip_bfloat16 h = __float2bfloat16(x);
  return *reinterpret_cast<unsigned short*>(&h);
}
__device__ __forceinline__ float bf2f(unsigned short b) {
  return __uint_as_float(((unsigned)b) << 16);
}
__device__ __forceinline__ float bflo(unsigned u) { return __uint_as_float(u << 16); }
__device__ __forceinline__ float bfhi(unsigned u) { return __uint_as_float(u & 0xffff0000u); }

// ---- fp8 e4m3 HW converts (gfx950 OCP; encode/decode self-consistent) ----
__device__ __forceinline__ unsigned char f2f8(float v) {
  return (unsigned char)(__builtin_amdgcn_cvt_pk_fp8_f32(v, v, 0, false) & 0xff);
}
template <int SEL>
__device__ __forceinline__ float f8dec(unsigned u) {
  return __builtin_amdgcn_cvt_f32_fp8((int)u, SEL);
}

// ---------------- merged weight-pack + edge histogram ----------------
__global__ void k_wtp_hist(const float* __restrict__ m1, const float* __restrict__ m2,
                           const float* __restrict__ wa, const float* __restrict__ pw,
                           uint4* __restrict__ outp,
                           const int* __restrict__ edge, int* __restrict__ cnt) {
  if (blockIdx.x < WTP_BLOCKS) {
    const int NH = 7 * 24 * 192;
    const int NP = 16 * 192;
    int idx = blockIdx.x * 256 + threadIdx.x;
    if (idx >= NH + NP) return;
    union { uint4 u; unsigned short h[8]; } fr;
    if (idx < NH) {
      int mat = idx / (24 * 192);
      int rem = idx - mat * (24 * 192);
      int kidx = rem / 192, col = rem - kidx * 192;
      const float* src = mat < 3 ? m1 + (size_t)mat * (DIM_H * DIM_H)
                       : (mat < 6 ? m2 + (size_t)(mat - 3) * (DIM_H * DIM_H) : wa);
#pragma unroll
      for (int t = 0; t < 8; ++t) fr.h[t] = f2bf(src[(size_t)(kidx * 8 + t) * DIM_H + col]);
    } else {
      int rem = idx - NH;
      int kidx = rem / 192, col = rem - kidx * 192;
#pragma unroll
      for (int t = 0; t < 8; ++t) fr.h[t] = f2bf(pw[(size_t)(kidx * 8 + t) * DIM_H + col]);
    }
    outp[idx] = fr.u;
  } else {
    int e = (blockIdx.x - WTP_BLOCKS) * 256 + threadIdx.x;
    if (e < N_EDGES) atomicAdd(&cnt[edge[N_EDGES + e]], 1);
  }
}

// ---------------- CSR scan ----------------
__global__ void k_scanA(const int* __restrict__ deg, int* __restrict__ part, int* __restrict__ bsum) {
  __shared__ int buf[1024];
  int g = blockIdx.x * 1024 + threadIdx.x;
  int v = (g < N_NODES) ? deg[g] : 0;
  buf[threadIdx.x] = v;
  __syncthreads();
  for (int off = 1; off < 1024; off <<= 1) {
    int t = (threadIdx.x >= off) ? buf[threadIdx.x - off] : 0;
    __syncthreads();
    buf[threadIdx.x] += t;
    __syncthreads();
  }
  if (g < N_NODES) part[g] = buf[threadIdx.x];
  if (threadIdx.x == 1023) bsum[blockIdx.x] = buf[1023];
}

__global__ void k_scanC(const int* __restrict__ part, const int* __restrict__ bsum,
                        int* __restrict__ rowptr, int* __restrict__ cursor) {
  __shared__ int excl[64];
  int tid = threadIdx.x;
  if (tid < 64) {
    int own = (tid < SCAN_NBLK) ? bsum[tid] : 0;
    int v = own;
    for (int off = 1; off < 64; off <<= 1) {
      int t = __shfl_up(v, off);
      if (tid >= off) v += t;
    }
    excl[tid] = v - own;
  }
  __syncthreads();
  int g = blockIdx.x * 256 + tid;
  if (g == 0) { rowptr[0] = 0; cursor[0] = 0; }
  if (g < N_NODES) {
    int v = part[g] + excl[g >> 10];
    rowptr[g + 1] = v;
    if (g + 1 < N_NODES) cursor[g + 1] = v;
  }
}

__global__ void k_fill(const int* __restrict__ edge, int* __restrict__ cursor, int* __restrict__ csr) {
  int e = blockIdx.x * 256 + threadIdx.x;
  if (e < N_EDGES) {
    int s = edge[e];
    int d = edge[N_EDGES + e];
    int pos = atomicAdd(&cursor[d], 1);
    csr[pos] = s;
  }
}

// ---------------- bulk B loader + MFMA stage on pre-loaded B ----------------
template <int KS>
__device__ __forceinline__ void load_b(const uint4* __restrict__ Bp, int colbase, int kq, int lr,
                                       FragU (&b)[KS][3]) {
#pragma unroll
  for (int ks = 0; ks < KS; ++ks)
#pragma unroll
    for (int n = 0; n < 3; ++n)
      b[ks][n].u = Bp[(ks * 4 + kq) * 192 + colbase + n * 16 + lr];
}

template <int KS, int MT>
__device__ __forceinline__ void mfma_stage_pre(const uint4* a_lds, const FragU (&b)[KS][3],
                                               int kq, int lr, floatx4 (&acc)[MT][3]) {
#pragma unroll
  for (int ks = 0; ks < KS; ++ks) {
    int kidx = ks * 4 + kq;
    FragU a[MT];
#pragma unroll
    for (int m = 0; m < MT; ++m) a[m].u = a_lds[kidx * (MT * 16) + m * 16 + lr];
#pragma unroll
    for (int n = 0; n < 3; ++n)
#pragma unroll
      for (int m = 0; m < MT; ++m)
        acc[m][n] = __builtin_amdgcn_mfma_f32_16x16x32_bf16(a[m].s, b[ks][n].s, acc[m][n], 0, 0, 0);
  }
}

// ---------------- MFMA projection: C = relu(x_f32[M,128] @ W + b) -> fp8 ----------------
__global__ __launch_bounds__(256) void k_proj(const float* __restrict__ A,
                                              const uint4* __restrict__ Bp,
                                              const float* __restrict__ bias,
                                              unsigned char* __restrict__ C) {
  __shared__ uint4 a_lds[16 * 64];
  const int tid = threadIdx.x;
  const int rbase = blockIdx.x * 64;
  const int lane = tid & 63, w = tid >> 6;
  const int kq = lane >> 4, lr = lane & 15;
  const int colbase = w * 48;
  FragU b[4][3];
  load_b<4>(Bp, colbase, kq, lr, b);
#pragma unroll
  for (int i = 0; i < 4; ++i) {
    int row = tid >> 2, kidx = i * 4 + (tid & 3);
    int gr = rbase + row;
    gr = gr < N_NODES ? gr : N_NODES - 1;
    const float* ap = A + (size_t)gr * DIM_IN + kidx * 8;
    float4 v0 = *(const float4*)ap;
    float4 v1 = *(const float4*)(ap + 4);
    union { uint4 u; unsigned short h[8]; } fr;
    fr.h[0] = f2bf(v0.x); fr.h[1] = f2bf(v0.y); fr.h[2] = f2bf(v0.z); fr.h[3] = f2bf(v0.w);
    fr.h[4] = f2bf(v1.x); fr.h[5] = f2bf(v1.y); fr.h[6] = f2bf(v1.z); fr.h[7] = f2bf(v1.w);
    a_lds[kidx * 64 + row] = fr.u;
  }
  __syncthreads();
  floatx4 acc[4][3];
  floatx4 zero4 = {0.f, 0.f, 0.f, 0.f};
#pragma unroll
  for (int m = 0; m < 4; ++m)
#pragma unroll
    for (int n = 0; n < 3; ++n) acc[m][n] = zero4;
  mfma_stage_pre<4, 4>(a_lds, b, kq, lr, acc);
#pragma unroll
  for (int n = 0; n < 3; ++n) {
    int col = colbase + n * 16 + lr;
    float bb = bias[col];
#pragma unroll
    for (int m = 0; m < 4; ++m)
#pragma unroll
      for (int j = 0; j < 4; ++j) {
        int row = rbase + m * 16 + kq * 4 + j;
        if (row < N_NODES) C[(size_t)row * DIM_H + col] = f2f8(relu_f(acc[m][n][j] + bb));
      }
  }
}

// ---------------- mlp helpers (BM=32 tile) ----------------
__device__ __forceinline__ void z_epi32(floatx4 (&acc)[2][3], unsigned short* zl, const float* __restrict__ b1,
                                        int colbase, int kq, int lr) {
#pragma unroll
  for (int n = 0; n < 3; ++n) {
    int col = colbase + n * 16 + lr;
    float bb = b1[col];
#pragma unroll
    for (int m = 0; m < 2; ++m)
#pragma unroll
      for (int j = 0; j < 4; ++j) {
        int rowl = m * 16 + kq * 4 + j;
        zl[(col >> 3) * 256 + rowl * 8 + (col & 7)] = f2bf(relu_f(acc[m][n][j] + bb));
      }
  }
}

template <bool F8>
__device__ __forceinline__ void out_epi32(floatx4 (&acc)[2][3], void* __restrict__ Zout,
                                          const float* __restrict__ b2, int rb, int colbase, int kq, int lr,
                                          float (&s3)[3], float (&q3)[3]) {
#pragma unroll
  for (int n = 0; n < 3; ++n) {
    int col = colbase + n * 16 + lr;
    float bb = b2[col];
#pragma unroll
    for (int m = 0; m < 2; ++m)
#pragma unroll
      for (int j = 0; j < 4; ++j) {
        int row = rb + m * 16 + kq * 4 + j;
        if (row < N_NODES) {
          float v = acc[m][n][j] + bb;
          if (F8)
            ((unsigned char*)Zout)[(size_t)row * DIM_H + col] = f2f8(v);
          else
            ((unsigned short*)Zout)[(size_t)row * DIM_H + col] = f2bf(v);
          s3[n] += v;
          q3[n] += v * v;
        }
      }
  }
}

// ---------------- FUSED agg + MLP, BM=32 (grid 1563 = 6.1 blocks/CU) ----------------
// Phase 1: 4 waves x 8 nodes gather (fp8 rows, optional BN+relu fold) into the 12 KB
//          MFMA A-tile LDS (frag layout). Per-node math identical to old k_agg.
// Phase 2: Z = relu(A@W1+b1)@W2+b2 (+ BN shadow stats). B loaded per block (L2-hot).
template <bool BN, bool F8OUT>
__global__ __launch_bounds__(256, 6) void k_aggmlp32(
    const unsigned char* __restrict__ z, const int* __restrict__ rowptr,
    const int* __restrict__ csr, const float* __restrict__ statsPrev,
    const float* __restrict__ bng, const float* __restrict__ bnb,
    const float* __restrict__ eps, int l,
    const uint4* __restrict__ B1p, const float* __restrict__ b1,
    const uint4* __restrict__ B2p, const float* __restrict__ b2,
    void* __restrict__ Zout, float* __restrict__ statsOut) {
  __shared__ uint4 a_lds[24 * 32];  // 12 KB: A tile (frag layout), then z1, then stat scratch
  const int tid = threadIdx.x;
  const int rbase = blockIdx.x * 32;
  const int lane = tid & 63, w = tid >> 6;
  const int kq = lane >> 4, lr = lane & 15;
  const int colbase = w * 48;
  // per-lane BN coefs for the 4 gather columns (lanes 0-47)
  float4 sc4 = {1.f, 1.f, 1.f, 1.f}, sh4 = {0.f, 0.f, 0.f, 0.f};
  const int c = lane * 4;
  if (BN && lane < 48) {
    float4 st = {0.f, 0.f, 0.f, 0.f}, sq = {0.f, 0.f, 0.f, 0.f};
#pragma unroll
    for (int g = 0; g < NSHADOW; ++g) {
      const float* sp = statsPrev + g * SSTRIDE;
      float4 a = *(const float4*)(sp + c);
      float4 b = *(const float4*)(sp + DIM_H + c);
      st.x += a.x; st.y += a.y; st.z += a.z; st.w += a.w;
      sq.x += b.x; sq.y += b.y; sq.z += b.z; sq.w += b.w;
    }
    float4 g4 = *(const float4*)(bng + c);
    float4 b4 = *(const float4*)(bnb + c);
    float mu, rs;
    mu = st.x * INV_N; rs = rsqrtf(sq.x * INV_N - mu * mu + BN_EPSF); sc4.x = g4.x * rs; sh4.x = b4.x - mu * sc4.x;
    mu = st.y * INV_N; rs = rsqrtf(sq.y * INV_N - mu * mu + BN_EPSF); sc4.y = g4.y * rs; sh4.y = b4.y - mu * sc4.y;
    mu = st.z * INV_N; rs = rsqrtf(sq.z * INV_N - mu * mu + BN_EPSF); sc4.z = g4.z * rs; sh4.z = b4.z - mu * sc4.z;
    mu = st.w * INV_N; rs = rsqrtf(sq.w * INV_N - mu * mu + BN_EPSF); sc4.w = g4.w * rs; sh4.w = b4.w - mu * sc4.w;
  }
  const float ep = 1.f + eps[l];
  // gather: wave w owns rows [w*8, w*8+8) of the 32-row tile
  for (int rr = 0; rr < 8; ++rr) {
    int r = w * 8 + rr;
    int node = rbase + r;
    node = node < N_NODES ? node : N_NODES - 1;
    if (lane < 48) {
      int beg = rowptr[node], end = rowptr[node + 1];
      unsigned us = *(const unsigned*)(z + (size_t)node * DIM_H + c);  // self row in flight
      float a0 = 0.f, a1 = 0.f, a2 = 0.f, a3 = 0.f;
#define ACCU(U)                                                          \
      {                                                                  \
        float v0 = f8dec<0>(U), v1 = f8dec<1>(U);                        \
        float v2 = f8dec<2>(U), v3 = f8dec<3>(U);                        \
        if (BN) {                                                        \
          v0 = relu_f(fmaf(v0, sc4.x, sh4.x));                           \
          v1 = relu_f(fmaf(v1, sc4.y, sh4.y));                           \
          v2 = relu_f(fmaf(v2, sc4.z, sh4.z));                           \
          v3 = relu_f(fmaf(v3, sc4.w, sh4.w));                           \
        }                                                                \
        a0 += v0; a1 += v1; a2 += v2; a3 += v3;                          \
      }
      int j = beg;
      for (; j + 4 <= end; j += 4) {
        int s0 = csr[j], s1 = csr[j + 1], s2 = csr[j + 2], s3 = csr[j + 3];
        unsigned u0 = *(const unsigned*)(z + (size_t)s0 * DIM_H + c);
        unsigned u1 = *(const unsigned*)(z + (size_t)s1 * DIM_H + c);
        unsigned u2 = *(const unsigned*)(z + (size_t)s2 * DIM_H + c);
        unsigned u3 = *(const unsigned*)(z + (size_t)s3 * DIM_H + c);
        ACCU(u0) ACCU(u1) ACCU(u2) ACCU(u3)
      }
      for (; j < end; ++j) {
        int s0 = csr[j];
        unsigned u0 = *(const unsigned*)(z + (size_t)s0 * DIM_H + c);
        ACCU(u0)
      }
#undef ACCU
      {
        float v0 = f8dec<0>(us), v1 = f8dec<1>(us), v2 = f8dec<2>(us), v3 = f8dec<3>(us);
        if (BN) {
          v0 = relu_f(fmaf(v0, sc4.x, sh4.x));
          v1 = relu_f(fmaf(v1, sc4.y, sh4.y));
          v2 = relu_f(fmaf(v2, sc4.z, sh4.z));
          v3 = relu_f(fmaf(v3, sc4.w, sh4.w));
        }
        a0 += ep * v0; a1 += ep * v1; a2 += ep * v2; a3 += ep * v3;
      }
      // write aggregated 4 bf16 cols into A-tile frag layout (rowl = r, 32-row tile)
      unsigned short* zl = (unsigned short*)a_lds;
      int pos = ((c >> 3) * 32 + r) * 8 + (c & 7);
      uint2 o;
      o.x = (unsigned)f2bf(a0) | ((unsigned)f2bf(a1) << 16);
      o.y = (unsigned)f2bf(a2) | ((unsigned)f2bf(a3) << 16);
      *(uint2*)(zl + pos) = o;
    }
  }
  // stage-1 B batch (completes behind the barrier)
  FragU b1r[6][3];
  load_b<6>(B1p, colbase, kq, lr, b1r);
  __syncthreads();
  // ---- MLP phase (single 32-row tile) ----
  floatx4 zero4 = {0.f, 0.f, 0.f, 0.f};
  floatx4 acc[2][3];
#pragma unroll
  for (int m = 0; m < 2; ++m)
#pragma unroll
    for (int n = 0; n < 3; ++n) acc[m][n] = zero4;
  mfma_stage_pre<6, 2>(a_lds, b1r, kq, lr, acc);
  FragU b2r[6][3];
  load_b<6>(B2p, colbase, kq, lr, b2r);
  __syncthreads();
  z_epi32(acc, (unsigned short*)a_lds, b1, colbase, kq, lr);
  __syncthreads();
#pragma unroll
  for (int m = 0; m < 2; ++m)
#pragma unroll
    for (int n = 0; n < 3; ++n) acc[m][n] = zero4;
  mfma_stage_pre<6, 2>(a_lds, b2r, kq, lr, acc);
  float s3[3] = {0.f, 0.f, 0.f}, q3[3] = {0.f, 0.f, 0.f};
  out_epi32<F8OUT>(acc, Zout, b2, rbase, colbase, kq, lr, s3, q3);
  __syncthreads();
  float* ps = (float*)a_lds;       // [192][4]
  float* pq = ps + DIM_H * 4;      // [192][4]
#pragma unroll
  for (int n = 0; n < 3; ++n) {
    int col = colbase + n * 16 + lr;
    ps[col * 4 + kq] = s3[n];
    pq[col * 4 + kq] = q3[n];
  }
  __syncthreads();
  if (tid < DIM_H) {
    float ts = 0.f, tq = 0.f;
#pragma unroll
    for (int g = 0; g < 4; ++g) {
      ts += ps[tid * 4 + g];
      tq += pq[tid * 4 + g];
    }
    float* sp = statsOut + (blockIdx.x & (NSHADOW - 1)) * SSTRIDE;
    atomicAdd(&sp[tid], ts);
    atomicAdd(&sp[DIM_H + tid], tq);
  }
}

// ---------------- attention + seed-proj + readout partials, all fused ----------------
__global__ __launch_bounds__(256, 3) void k_attnm(const unsigned short* __restrict__ Zin,
                                                  const float* __restrict__ stats,
                                                  const float* __restrict__ bng,
                                                  const float* __restrict__ bnb,
                                                  const uint4* __restrict__ Bp,
                                                  const int* __restrict__ seedp,
                                                  const float* __restrict__ W2,
                                                  const float* __restrict__ wat,
                                                  float* __restrict__ p, float* __restrict__ scal,
                                                  float* __restrict__ rdoutS) {
  __shared__ uint4 a_lds[24 * 64];   // BN'd h tile, preserved for readout
  __shared__ float part[64][65];
  __shared__ float cs[DIM_H], ch[DIM_H], hs[DIM_H], s2l[DIM_H];
  __shared__ float pe_lds[64];
  const int tid = threadIdx.x;
  const int rbase = blockIdx.x * 64;
  const int lane = tid & 63, w = tid >> 6;
  const int kq = lane >> 4, lr = lane & 15;
  const int colbase = w * 48;
  FragU b[6][3];
  load_b<6>(Bp, colbase, kq, lr, b);
  if (tid < DIM_H) {
    float ts = 0.f, tq = 0.f;
#pragma unroll
    for (int g = 0; g < NSHADOW; ++g) {
      ts += stats[g * SSTRIDE + tid];
      tq += stats[g * SSTRIDE + DIM_H + tid];
    }
    float mu = ts * INV_N;
    float rs = rsqrtf(tq * INV_N - mu * mu + BN_EPSF);
    float sc = bng[tid] * rs;
    float sh = bnb[tid] - mu * sc;
    cs[tid] = sc;
    ch[tid] = sh;
    int seed = seedp[0];
    hs[tid] = relu_f(bf2f(Zin[(size_t)seed * DIM_H + tid]) * sc + sh);
  }
  __syncthreads();
#pragma unroll
  for (int i = 0; i < 6; ++i) {
    int row = tid >> 2, kidx = i * 4 + (tid & 3);
    int gr = rbase + row;
    gr = gr < N_NODES ? gr : N_NODES - 1;
    union { uint4 u; unsigned short h[8]; } v, o;
    v.u = *(const uint4*)(Zin + (size_t)gr * DIM_H + kidx * 8);
#pragma unroll
    for (int t = 0; t < 8; ++t)
      o.h[t] = f2bf(relu_f(bf2f(v.h[t]) * cs[kidx * 8 + t] + ch[kidx * 8 + t]));
    a_lds[kidx * 64 + row] = o.u;
  }
  if (tid < DIM_H) {
    float t0 = 0.f, t1 = 0.f, t2 = 0.f, t3 = 0.f;
    for (int k = 0; k < DIM_H; k += 4) {
      t0 = fmaf(hs[k + 0], W2[(size_t)(k + 0) * DIM_H + tid], t0);
      t1 = fmaf(hs[k + 1], W2[(size_t)(k + 1) * DIM_H + tid], t1);
      t2 = fmaf(hs[k + 2], W2[(size_t)(k + 2) * DIM_H + tid], t2);
      t3 = fmaf(hs[k + 3], W2[(size_t)(k + 3) * DIM_H + tid], t3);
    }
    s2l[tid] = (t0 + t1) + (t2 + t3);
  }
  __syncthreads();
  floatx4 zero4 = {0.f, 0.f, 0.f, 0.f};
  floatx4 acc[4][3];
#pragma unroll
  for (int m = 0; m < 4; ++m)
#pragma unroll
    for (int n = 0; n < 3; ++n) acc[m][n] = zero4;
  mfma_stage_pre<6, 4>(a_lds, b, kq, lr, acc);
  float pv[16];
#pragma unroll
  for (int t = 0; t < 16; ++t) pv[t] = 0.f;
#pragma unroll
  for (int n = 0; n < 3; ++n) {
    int col = colbase + n * 16 + lr;
    float s2c = s2l[col];
    float wv = wat[col];
#pragma unroll
    for (int m = 0; m < 4; ++m)
#pragma unroll
      for (int j = 0; j < 4; ++j) {
        float xv = acc[m][n][j] + s2c;
        xv = fminf(fmaxf(xv, -10.f), 10.f);
        float t = __expf(2.f * xv);
        pv[m * 4 + j] = fmaf((t - 1.f) / (t + 1.f), wv, pv[m * 4 + j]);
      }
  }
#pragma unroll
  for (int m = 0; m < 4; ++m)
#pragma unroll
    for (int j = 0; j < 4; ++j)
      part[m * 16 + kq * 4 + j][w * 16 + lr] = pv[m * 4 + j];
  __syncthreads();
  if (tid < 64) {
    float s = 0.f;
#pragma unroll
    for (int i = 0; i < 64; ++i) s += part[tid][i];
    s = s > 0.f ? s : 0.2f * s;
    float pe = __expf(s);
    int gr = rbase + tid;
    bool valid = gr < N_NODES;
    if (valid) p[gr] = pe;
    pe = valid ? pe : 0.f;
    pe_lds[tid] = pe;
    float red = pe;
#pragma unroll
    for (int off = 32; off > 0; off >>= 1) red += __shfl_xor(red, off);
    if (tid == 0) atomicAdd(&scal[0], red);
  }
  __syncthreads();
  if (tid < DIM_H) {
    const unsigned short* al = (const unsigned short*)a_lds;
    int base = (tid >> 3) * 512 + (tid & 7);
    float s = 0.f;
    for (int it = 0; it < 64; ++it) {
      int row = (it + tid) & 63;
      s = fmaf(pe_lds[row], bf2f(al[base + row * 8]), s);
    }
    atomicAdd(&rdoutS[(blockIdx.x & (NSHADOW - 1)) * DIM_H + tid], s);
  }
}

// ---------------- alpha = p / S ----------------
__global__ void k_alpha(const float* __restrict__ p, const float* __restrict__ scal,
                        float* __restrict__ alpha) {
  int i = blockIdx.x * 256 + threadIdx.x;
  if (i < N_NODES) alpha[i] = p[i] * (1.f / scal[0]);
}

__global__ void k_logit(const float* __restrict__ rdoutS, const float* __restrict__ scal,
                        const float* __restrict__ cw, const float* __restrict__ cb,
                        float* __restrict__ out) {
  __shared__ float buf[256];
  int tid = threadIdx.x;
  float v = 0.f;
  if (tid < DIM_H) {
    float s = 0.f;
#pragma unroll
    for (int g = 0; g < NSHADOW; ++g) s += rdoutS[g * DIM_H + tid];
    v = s * cw[tid];
  }
  buf[tid] = v;
  __syncthreads();
  for (int s = 128; s > 0; s >>= 1) {
    if (tid < s) buf[tid] += buf[tid + s];
    __syncthreads();
  }
  if (tid == 0) out[0] = buf[0] * (1.f / scal[0]) + cb[0];
}

extern "C" void kernel_launch(void* const* d_in, const int* in_sizes, int n_in,
                              void* d_out, int out_size, void* d_ws, size_t ws_size,
                              hipStream_t stream) {
  const float* x      = (const float*)d_in[0];
  const int*   edge   = (const int*)d_in[1];
  const int*   seedp  = (const int*)d_in[2];
  const float* proj_w = (const float*)d_in[3];
  const float* proj_b = (const float*)d_in[4];
  const float* mlp1_w = (const float*)d_in[5];
  const float* mlp1_b = (const float*)d_in[6];
  const float* mlp2_w = (const float*)d_in[7];
  const float* mlp2_b = (const float*)d_in[8];
  const float* eps    = (const float*)d_in[9];
  const float* bn_g   = (const float*)d_in[10];
  const float* bn_b   = (const float*)d_in[11];
  const float* W1     = (const float*)d_in[12];
  const float* W2     = (const float*)d_in[13];
  const float* w_attn = (const float*)d_in[14];
  const float* cls_w  = (const float*)d_in[15];
  const float* cls_b  = (const float*)d_in[16];
  float* out = (float*)d_out;

  char* ws = (char*)d_ws;
  size_t off = 0;
  auto alloc = [&](size_t bytes) -> void* {
    void* p = ws + off;
    off = (off + bytes + 255) & ~(size_t)255;
    return p;
  };
  unsigned char*  f8a = (unsigned char*)alloc((size_t)N_NODES * DIM_H);       // fp8 h0 / z2
  unsigned char*  f8b = (unsigned char*)alloc((size_t)N_NODES * DIM_H);       // fp8 z1
  unsigned short* zbf = (unsigned short*)alloc((size_t)N_NODES * DIM_H * 2);  // bf16 z3
  float* pbuf   = (float*)alloc((size_t)N_NODES * 4);
  int* rowptr   = (int*)alloc((size_t)(N_NODES + 1) * 4);
  int* csr      = (int*)alloc((size_t)N_EDGES * 4);
  int* part     = (int*)alloc((size_t)N_NODES * 4);
  int* bsum     = (int*)alloc(64 * 4);
  // ---- zero-initialized span: cursor + stats[3 layers] + scal + rdout shadows ----
  size_t zbeg = off;
  int* cursor   = (int*)alloc((size_t)(N_NODES + 1) * 4);
  float* statsA = (float*)alloc((size_t)N_LAYERS * NSHADOW * SSTRIDE * 4);
  float* scalrd = (float*)alloc((size_t)(64 + NSHADOW * DIM_H) * 4);
  size_t zend = off;
  float* scal   = scalrd;
  float* rdoutS = scalrd + 64;
  uint4* WTall  = (uint4*)alloc((size_t)(7 * 24 * 192 + 16 * 192) * 16);

  float* statsL[N_LAYERS];
  for (int l = 0; l < N_LAYERS; ++l) statsL[l] = statsA + (size_t)l * NSHADOW * SSTRIDE;

  const uint4* B1p[N_LAYERS] = {WTall, WTall + 4608, WTall + 2 * 4608};
  const uint4* B2p[N_LAYERS] = {WTall + 3 * 4608, WTall + 4 * 4608, WTall + 5 * 4608};
  const uint4* Bap = WTall + 6 * 4608;
  const uint4* Bpp = WTall + 7 * 4608;

  const int GRID64 = (N_NODES + 63) / 64;   // 782
  const int GRID32 = (N_NODES + 31) / 32;   // 1563

  hipMemsetAsync(ws + zbeg, 0, zend - zbeg, stream);

  // weight pack + edge histogram (merged)
  k_wtp_hist<<<WTP_BLOCKS + (N_EDGES + 255) / 256, 256, 0, stream>>>(
      mlp1_w, mlp2_w, W1, proj_w, WTall, edge, cursor);

  // CSR build
  k_scanA<<<SCAN_NBLK, 1024, 0, stream>>>(cursor, part, bsum);
  k_scanC<<<(N_NODES + 255) / 256, 256, 0, stream>>>(part, bsum, rowptr, cursor);
  k_fill<<<(N_EDGES + 255) / 256, 256, 0, stream>>>(edge, cursor, csr);

  // projection: x -> f8a (relu'd h0, fp8)
  k_proj<<<GRID64, 256, 0, stream>>>(x, Bpp, proj_b, f8a);

  // fused agg+MLP layers (BM=32, 6 blocks/CU)
  k_aggmlp32<false, true><<<GRID32, 256, 0, stream>>>(
      f8a, rowptr, csr, statsL[0], bn_g, bn_b, eps, 0,
      B1p[0], mlp1_b, B2p[0], mlp2_b, f8b, statsL[0]);
  k_aggmlp32<true, true><<<GRID32, 256, 0, stream>>>(
      f8b, rowptr, csr, statsL[0], bn_g, bn_b, eps, 1,
      B1p[1], mlp1_b + DIM_H, B2p[1], mlp2_b + DIM_H, f8a, statsL[1]);
  k_aggmlp32<true, false><<<GRID32, 256, 0, stream>>>(
      f8a, rowptr, csr, statsL[1], bn_g + DIM_H, bn_b + DIM_H, eps, 2,
      B1p[2], mlp1_b + 2 * DIM_H, B2p[2], mlp2_b + 2 * DIM_H, zbf, statsL[2]);

  // final: BN (statsL[2] + bn[2]) fused; attnm also does seed-proj + readout partials
  const float* g2 = bn_g + (size_t)2 * DIM_H;
  const float* b2c = bn_b + (size_t)2 * DIM_H;

  k_attnm<<<GRID64, 256, 0, stream>>>(zbf, statsL[2], g2, b2c, Bap, seedp, W2, w_attn, pbuf, scal, rdoutS);
  k_alpha<<<(N_NODES + 255) / 256, 256, 0, stream>>>(pbuf, scal, out + 1);
  k_logit<<<1, 256, 0, stream>>>(rdoutS, scal, cls_w, cls_b, out);
}

// Round 17
// 288.373 us; speedup vs baseline: 1.1974x; 1.1974x over previous
//
#include <hip/hip_runtime.h>
#include <hip/hip_bf16.h>

#define N_NODES 50000
#define N_EDGES 400000
#define DIM_IN  128
#define DIM_H   192
#define N_LAYERS 3
#define BN_EPSF 1e-5f
#define SCAN_NBLK 49  // ceil(50000/1024)
#define INV_N (1.f / N_NODES)
#define NSHADOW 8
#define SSTRIDE 384   // per-shadow: [0..191]=sum, [192..383]=sumsq
#define WTP_BLOCKS 138  // ceil((7*24*192 + 16*192)/256)

typedef __attribute__((ext_vector_type(8))) short short8;
typedef __attribute__((ext_vector_type(4))) float floatx4;

union FragU { uint4 u; short8 s; };

__device__ __forceinline__ float relu_f(float x) { return x > 0.f ? x : 0.f; }
__device__ __forceinline__ unsigned short f2bf(float x) {
  __hip_bfloat16 h = __float2bfloat16(x);
  return *reinterpret_cast<unsigned short*>(&h);
}
__device__ __forceinline__ float bf2f(unsigned short b) {
  return __uint_as_float(((unsigned)b) << 16);
}
__device__ __forceinline__ float bflo(unsigned u) { return __uint_as_float(u << 16); }
__device__ __forceinline__ float bfhi(unsigned u) { return __uint_as_float(u & 0xffff0000u); }

// ---- fp8 e4m3 HW converts (gfx950 OCP; encode/decode self-consistent) ----
__device__ __forceinline__ unsigned char f2f8(float v) {
  return (unsigned char)(__builtin_amdgcn_cvt_pk_fp8_f32(v, v, 0, false) & 0xff);
}
template <int SEL>
__device__ __forceinline__ float f8dec(unsigned u) {
  return __builtin_amdgcn_cvt_f32_fp8((int)u, SEL);
}

// ---------------- merged weight-pack + edge histogram ----------------
__global__ void k_wtp_hist(const float* __restrict__ m1, const float* __restrict__ m2,
                           const float* __restrict__ wa, const float* __restrict__ pw,
                           uint4* __restrict__ outp,
                           const int* __restrict__ edge, int* __restrict__ cnt) {
  if (blockIdx.x < WTP_BLOCKS) {
    const int NH = 7 * 24 * 192;
    const int NP = 16 * 192;
    int idx = blockIdx.x * 256 + threadIdx.x;
    if (idx >= NH + NP) return;
    union { uint4 u; unsigned short h[8]; } fr;
    if (idx < NH) {
      int mat = idx / (24 * 192);
      int rem = idx - mat * (24 * 192);
      int kidx = rem / 192, col = rem - kidx * 192;
      const float* src = mat < 3 ? m1 + (size_t)mat * (DIM_H * DIM_H)
                       : (mat < 6 ? m2 + (size_t)(mat - 3) * (DIM_H * DIM_H) : wa);
#pragma unroll
      for (int t = 0; t < 8; ++t) fr.h[t] = f2bf(src[(size_t)(kidx * 8 + t) * DIM_H + col]);
    } else {
      int rem = idx - NH;
      int kidx = rem / 192, col = rem - kidx * 192;
#pragma unroll
      for (int t = 0; t < 8; ++t) fr.h[t] = f2bf(pw[(size_t)(kidx * 8 + t) * DIM_H + col]);
    }
    outp[idx] = fr.u;
  } else {
    int e = (blockIdx.x - WTP_BLOCKS) * 256 + threadIdx.x;
    if (e < N_EDGES) atomicAdd(&cnt[edge[N_EDGES + e]], 1);
  }
}

// ---------------- CSR scan ----------------
__global__ void k_scanA(const int* __restrict__ deg, int* __restrict__ part, int* __restrict__ bsum) {
  __shared__ int buf[1024];
  int g = blockIdx.x * 1024 + threadIdx.x;
  int v = (g < N_NODES) ? deg[g] : 0;
  buf[threadIdx.x] = v;
  __syncthreads();
  for (int off = 1; off < 1024; off <<= 1) {
    int t = (threadIdx.x >= off) ? buf[threadIdx.x - off] : 0;
    __syncthreads();
    buf[threadIdx.x] += t;
    __syncthreads();
  }
  if (g < N_NODES) part[g] = buf[threadIdx.x];
  if (threadIdx.x == 1023) bsum[blockIdx.x] = buf[1023];
}

__global__ void k_scanC(const int* __restrict__ part, const int* __restrict__ bsum,
                        int* __restrict__ rowptr, int* __restrict__ cursor) {
  __shared__ int excl[64];
  int tid = threadIdx.x;
  if (tid < 64) {
    int own = (tid < SCAN_NBLK) ? bsum[tid] : 0;
    int v = own;
    for (int off = 1; off < 64; off <<= 1) {
      int t = __shfl_up(v, off);
      if (tid >= off) v += t;
    }
    excl[tid] = v - own;
  }
  __syncthreads();
  int g = blockIdx.x * 256 + tid;
  if (g == 0) { rowptr[0] = 0; cursor[0] = 0; }
  if (g < N_NODES) {
    int v = part[g] + excl[g >> 10];
    rowptr[g + 1] = v;
    if (g + 1 < N_NODES) cursor[g + 1] = v;
  }
}

__global__ void k_fill(const int* __restrict__ edge, int* __restrict__ cursor, int* __restrict__ csr) {
  int e = blockIdx.x * 256 + threadIdx.x;
  if (e < N_EDGES) {
    int s = edge[e];
    int d = edge[N_EDGES + e];
    int pos = atomicAdd(&cursor[d], 1);
    csr[pos] = s;
  }
}

// ---------------- aggregation: fp8 gather, 1 node/wave, lanes 0-47, 4 cols each ----------------
template <bool BN>
__global__ void k_agg(const unsigned char* __restrict__ z, const int* __restrict__ rowptr,
                      const int* __restrict__ csr, const float* __restrict__ stats,
                      const float* __restrict__ bng, const float* __restrict__ bnb,
                      const float* __restrict__ eps, int l, unsigned short* __restrict__ outA) {
  int wid = threadIdx.x >> 6, lane = threadIdx.x & 63;
  int node = blockIdx.x * 4 + wid;
  if (node >= N_NODES || lane >= 48) return;
  int c = lane * 4;
  float4 sc4 = {1.f, 1.f, 1.f, 1.f}, sh4 = {0.f, 0.f, 0.f, 0.f};
  if (BN) {
    float4 st = {0.f, 0.f, 0.f, 0.f}, sq = {0.f, 0.f, 0.f, 0.f};
#pragma unroll
    for (int g = 0; g < NSHADOW; ++g) {
      const float* sp = stats + g * SSTRIDE;
      float4 a = *(const float4*)(sp + c);
      float4 b = *(const float4*)(sp + DIM_H + c);
      st.x += a.x; st.y += a.y; st.z += a.z; st.w += a.w;
      sq.x += b.x; sq.y += b.y; sq.z += b.z; sq.w += b.w;
    }
    float4 g4 = *(const float4*)(bng + c);
    float4 b4 = *(const float4*)(bnb + c);
    float mu, rs;
    mu = st.x * INV_N; rs = rsqrtf(sq.x * INV_N - mu * mu + BN_EPSF); sc4.x = g4.x * rs; sh4.x = b4.x - mu * sc4.x;
    mu = st.y * INV_N; rs = rsqrtf(sq.y * INV_N - mu * mu + BN_EPSF); sc4.y = g4.y * rs; sh4.y = b4.y - mu * sc4.y;
    mu = st.z * INV_N; rs = rsqrtf(sq.z * INV_N - mu * mu + BN_EPSF); sc4.z = g4.z * rs; sh4.z = b4.z - mu * sc4.z;
    mu = st.w * INV_N; rs = rsqrtf(sq.w * INV_N - mu * mu + BN_EPSF); sc4.w = g4.w * rs; sh4.w = b4.w - mu * sc4.w;
  }
  float a0 = 0.f, a1 = 0.f, a2 = 0.f, a3 = 0.f;
  int beg = rowptr[node], end = rowptr[node + 1];
  unsigned us = *(const unsigned*)(z + (size_t)node * DIM_H + c);
#define ACCU(U)                                                          \
  {                                                                      \
    float v0 = f8dec<0>(U), v1 = f8dec<1>(U);                            \
    float v2 = f8dec<2>(U), v3 = f8dec<3>(U);                            \
    if (BN) {                                                            \
      v0 = relu_f(fmaf(v0, sc4.x, sh4.x));                               \
      v1 = relu_f(fmaf(v1, sc4.y, sh4.y));                               \
      v2 = relu_f(fmaf(v2, sc4.z, sh4.z));                               \
      v3 = relu_f(fmaf(v3, sc4.w, sh4.w));                               \
    }                                                                    \
    a0 += v0; a1 += v1; a2 += v2; a3 += v3;                              \
  }
  int j = beg;
  for (; j + 4 <= end; j += 4) {
    int s0 = csr[j], s1 = csr[j + 1], s2 = csr[j + 2], s3 = csr[j + 3];
    unsigned u0 = *(const unsigned*)(z + (size_t)s0 * DIM_H + c);
    unsigned u1 = *(const unsigned*)(z + (size_t)s1 * DIM_H + c);
    unsigned u2 = *(const unsigned*)(z + (size_t)s2 * DIM_H + c);
    unsigned u3 = *(const unsigned*)(z + (size_t)s3 * DIM_H + c);
    ACCU(u0) ACCU(u1) ACCU(u2) ACCU(u3)
  }
  for (; j < end; ++j) {
    int s0 = csr[j];
    unsigned u0 = *(const unsigned*)(z + (size_t)s0 * DIM_H + c);
    ACCU(u0)
  }
#undef ACCU
  float ep = 1.f + eps[l];
  {
    float v0 = f8dec<0>(us), v1 = f8dec<1>(us), v2 = f8dec<2>(us), v3 = f8dec<3>(us);
    if (BN) {
      v0 = relu_f(fmaf(v0, sc4.x, sh4.x));
      v1 = relu_f(fmaf(v1, sc4.y, sh4.y));
      v2 = relu_f(fmaf(v2, sc4.z, sh4.z));
      v3 = relu_f(fmaf(v3, sc4.w, sh4.w));
    }
    a0 += ep * v0; a1 += ep * v1; a2 += ep * v2; a3 += ep * v3;
  }
  uint2 o;
  o.x = (unsigned)f2bf(a0) | ((unsigned)f2bf(a1) << 16);
  o.y = (unsigned)f2bf(a2) | ((unsigned)f2bf(a3) << 16);
  *(uint2*)(outA + (size_t)node * DIM_H + c) = o;
}

// ---------------- bulk B loader + MFMA stage on pre-loaded B ----------------
template <int KS>
__device__ __forceinline__ void load_b(const uint4* __restrict__ Bp, int colbase, int kq, int lr,
                                       FragU (&b)[KS][3]) {
#pragma unroll
  for (int ks = 0; ks < KS; ++ks)
#pragma unroll
    for (int n = 0; n < 3; ++n)
      b[ks][n].u = Bp[(ks * 4 + kq) * 192 + colbase + n * 16 + lr];
}

template <int KS, int MT>
__device__ __forceinline__ void mfma_stage_pre(const uint4* a_lds, const FragU (&b)[KS][3],
                                               int kq, int lr, floatx4 (&acc)[MT][3]) {
#pragma unroll
  for (int ks = 0; ks < KS; ++ks) {
    int kidx = ks * 4 + kq;
    FragU a[MT];
#pragma unroll
    for (int m = 0; m < MT; ++m) a[m].u = a_lds[kidx * (MT * 16) + m * 16 + lr];
#pragma unroll
    for (int n = 0; n < 3; ++n)
#pragma unroll
      for (int m = 0; m < MT; ++m)
        acc[m][n] = __builtin_amdgcn_mfma_f32_16x16x32_bf16(a[m].s, b[ks][n].s, acc[m][n], 0, 0, 0);
  }
}

// ---------------- MFMA projection: C = relu(x_f32[M,128] @ W + b) -> fp8 ----------------
__global__ __launch_bounds__(256) void k_proj(const float* __restrict__ A,
                                              const uint4* __restrict__ Bp,
                                              const float* __restrict__ bias,
                                              unsigned char* __restrict__ C) {
  __shared__ uint4 a_lds[16 * 64];
  const int tid = threadIdx.x;
  const int rbase = blockIdx.x * 64;
  const int lane = tid & 63, w = tid >> 6;
  const int kq = lane >> 4, lr = lane & 15;
  const int colbase = w * 48;
  FragU b[4][3];
  load_b<4>(Bp, colbase, kq, lr, b);
#pragma unroll
  for (int i = 0; i < 4; ++i) {
    int row = tid >> 2, kidx = i * 4 + (tid & 3);
    int gr = rbase + row;
    gr = gr < N_NODES ? gr : N_NODES - 1;
    const float* ap = A + (size_t)gr * DIM_IN + kidx * 8;
    float4 v0 = *(const float4*)ap;
    float4 v1 = *(const float4*)(ap + 4);
    union { uint4 u; unsigned short h[8]; } fr;
    fr.h[0] = f2bf(v0.x); fr.h[1] = f2bf(v0.y); fr.h[2] = f2bf(v0.z); fr.h[3] = f2bf(v0.w);
    fr.h[4] = f2bf(v1.x); fr.h[5] = f2bf(v1.y); fr.h[6] = f2bf(v1.z); fr.h[7] = f2bf(v1.w);
    a_lds[kidx * 64 + row] = fr.u;
  }
  __syncthreads();
  floatx4 acc[4][3];
  floatx4 zero4 = {0.f, 0.f, 0.f, 0.f};
#pragma unroll
  for (int m = 0; m < 4; ++m)
#pragma unroll
    for (int n = 0; n < 3; ++n) acc[m][n] = zero4;
  mfma_stage_pre<4, 4>(a_lds, b, kq, lr, acc);
#pragma unroll
  for (int n = 0; n < 3; ++n) {
    int col = colbase + n * 16 + lr;
    float bb = bias[col];
#pragma unroll
    for (int m = 0; m < 4; ++m)
#pragma unroll
      for (int j = 0; j < 4; ++j) {
        int row = rbase + m * 16 + kq * 4 + j;
        if (row < N_NODES) C[(size_t)row * DIM_H + col] = f2f8(relu_f(acc[m][n][j] + bb));
      }
  }
}

// ---------------- k_mlp helpers ----------------
__device__ __forceinline__ void z_epi(floatx4 (&acc)[2][3], unsigned short* zl, const float* __restrict__ b1,
                                      int colbase, int kq, int lr) {
#pragma unroll
  for (int n = 0; n < 3; ++n) {
    int col = colbase + n * 16 + lr;
    float bb = b1[col];
#pragma unroll
    for (int m = 0; m < 2; ++m)
#pragma unroll
      for (int j = 0; j < 4; ++j) {
        int rowl = m * 16 + kq * 4 + j;
        zl[(col >> 3) * 256 + rowl * 8 + (col & 7)] = f2bf(relu_f(acc[m][n][j] + bb));
      }
  }
}

template <bool F8>
__device__ __forceinline__ void out_epi(floatx4 (&acc)[2][3], void* __restrict__ Zout,
                                        const float* __restrict__ b2, int rb, int colbase, int kq, int lr,
                                        float (&s3)[3], float (&q3)[3]) {
#pragma unroll
  for (int n = 0; n < 3; ++n) {
    int col = colbase + n * 16 + lr;
    float bb = b2[col];
#pragma unroll
    for (int m = 0; m < 2; ++m)
#pragma unroll
      for (int j = 0; j < 4; ++j) {
        int row = rb + m * 16 + kq * 4 + j;
        if (row < N_NODES) {
          float v = acc[m][n][j] + bb;
          if (F8)
            ((unsigned char*)Zout)[(size_t)row * DIM_H + col] = f2f8(v);
          else
            ((unsigned short*)Zout)[(size_t)row * DIM_H + col] = f2bf(v);
          s3[n] += v;
          q3[n] += v * v;
        }
      }
  }
}

// ---------------- fused MLP (MFMA, BM=64 = 2x32 tiles, B reused): Z = relu(A@W1+b1)@W2+b2 ----------------
template <bool F8>
__global__ __launch_bounds__(256, 3) void k_mlp(const unsigned short* __restrict__ A,
                                                const uint4* __restrict__ B1p, const float* __restrict__ b1,
                                                const uint4* __restrict__ B2p, const float* __restrict__ b2,
                                                void* __restrict__ Zout, float* __restrict__ stats) {
  __shared__ uint4 a_lds[2][24 * 32];
  const int tid = threadIdx.x;
  const int rbase = blockIdx.x * 64;
  const int lane = tid & 63, w = tid >> 6;
  const int kq = lane >> 4, lr = lane & 15;
  const int colbase = w * 48;
  uint4 areg[2][3];
  const int arow = tid >> 3;
#pragma unroll
  for (int t = 0; t < 2; ++t) {
    int agr = rbase + t * 32 + arow;
    agr = agr < N_NODES ? agr : N_NODES - 1;
#pragma unroll
    for (int i = 0; i < 3; ++i) {
      int kidx = i * 8 + (tid & 7);
      areg[t][i] = *(const uint4*)(A + (size_t)agr * DIM_H + kidx * 8);
    }
  }
  FragU b1r[6][3];
  load_b<6>(B1p, colbase, kq, lr, b1r);
#pragma unroll
  for (int t = 0; t < 2; ++t)
#pragma unroll
    for (int i = 0; i < 3; ++i) {
      int kidx = i * 8 + (tid & 7);
      a_lds[t][kidx * 32 + arow] = areg[t][i];
    }
  __syncthreads();
  floatx4 zero4 = {0.f, 0.f, 0.f, 0.f};
  floatx4 acc0[2][3], acc1[2][3];
#pragma unroll
  for (int m = 0; m < 2; ++m)
#pragma unroll
    for (int n = 0; n < 3; ++n) { acc0[m][n] = zero4; acc1[m][n] = zero4; }
  mfma_stage_pre<6, 2>(a_lds[0], b1r, kq, lr, acc0);
  mfma_stage_pre<6, 2>(a_lds[1], b1r, kq, lr, acc1);
  FragU b2r[6][3];
  load_b<6>(B2p, colbase, kq, lr, b2r);
  __syncthreads();
  z_epi(acc0, (unsigned short*)a_lds[0], b1, colbase, kq, lr);
  z_epi(acc1, (unsigned short*)a_lds[1], b1, colbase, kq, lr);
  __syncthreads();
#pragma unroll
  for (int m = 0; m < 2; ++m)
#pragma unroll
    for (int n = 0; n < 3; ++n) { acc0[m][n] = zero4; acc1[m][n] = zero4; }
  mfma_stage_pre<6, 2>(a_lds[0], b2r, kq, lr, acc0);
  mfma_stage_pre<6, 2>(a_lds[1], b2r, kq, lr, acc1);
  float s3[3] = {0.f, 0.f, 0.f}, q3[3] = {0.f, 0.f, 0.f};
  out_epi<F8>(acc0, Zout, b2, rbase, colbase, kq, lr, s3, q3);
  out_epi<F8>(acc1, Zout, b2, rbase + 32, colbase, kq, lr, s3, q3);
  __syncthreads();
  float* ps = (float*)a_lds;
  float* pq = ps + DIM_H * 4;
#pragma unroll
  for (int n = 0; n < 3; ++n) {
    int col = colbase + n * 16 + lr;
    ps[col * 4 + kq] = s3[n];
    pq[col * 4 + kq] = q3[n];
  }
  __syncthreads();
  if (tid < DIM_H) {
    float ts = 0.f, tq = 0.f;
#pragma unroll
    for (int g = 0; g < 4; ++g) {
      ts += ps[tid * 4 + g];
      tq += pq[tid * 4 + g];
    }
    float* sp = stats + (blockIdx.x & (NSHADOW - 1)) * SSTRIDE;
    atomicAdd(&sp[tid], ts);
    atomicAdd(&sp[DIM_H + tid], tq);
  }
}

// ---------------- attention + seed-proj + readout partials, all fused ----------------
__global__ __launch_bounds__(256, 3) void k_attnm(const unsigned short* __restrict__ Zin,
                                                  const float* __restrict__ stats,
                                                  const float* __restrict__ bng,
                                                  const float* __restrict__ bnb,
                                                  const uint4* __restrict__ Bp,
                                                  const int* __restrict__ seedp,
                                                  const float* __restrict__ W2,
                                                  const float* __restrict__ wat,
                                                  float* __restrict__ p, float* __restrict__ scal,
                                                  float* __restrict__ rdoutS) {
  __shared__ uint4 a_lds[24 * 64];   // BN'd h tile, preserved for readout
  __shared__ float part[64][65];
  __shared__ float cs[DIM_H], ch[DIM_H], hs[DIM_H], s2l[DIM_H];
  __shared__ float pe_lds[64];
  const int tid = threadIdx.x;
  const int rbase = blockIdx.x * 64;
  const int lane = tid & 63, w = tid >> 6;
  const int kq = lane >> 4, lr = lane & 15;
  const int colbase = w * 48;
  FragU b[6][3];
  load_b<6>(Bp, colbase, kq, lr, b);
  if (tid < DIM_H) {
    float ts = 0.f, tq = 0.f;
#pragma unroll
    for (int g = 0; g < NSHADOW; ++g) {
      ts += stats[g * SSTRIDE + tid];
      tq += stats[g * SSTRIDE + DIM_H + tid];
    }
    float mu = ts * INV_N;
    float rs = rsqrtf(tq * INV_N - mu * mu + BN_EPSF);
    float sc = bng[tid] * rs;
    float sh = bnb[tid] - mu * sc;
    cs[tid] = sc;
    ch[tid] = sh;
    int seed = seedp[0];
    hs[tid] = relu_f(bf2f(Zin[(size_t)seed * DIM_H + tid]) * sc + sh);
  }
  __syncthreads();
#pragma unroll
  for (int i = 0; i < 6; ++i) {
    int row = tid >> 2, kidx = i * 4 + (tid & 3);
    int gr = rbase + row;
    gr = gr < N_NODES ? gr : N_NODES - 1;
    union { uint4 u; unsigned short h[8]; } v, o;
    v.u = *(const uint4*)(Zin + (size_t)gr * DIM_H + kidx * 8);
#pragma unroll
    for (int t = 0; t < 8; ++t)
      o.h[t] = f2bf(relu_f(bf2f(v.h[t]) * cs[kidx * 8 + t] + ch[kidx * 8 + t]));
    a_lds[kidx * 64 + row] = o.u;
  }
  if (tid < DIM_H) {
    float t0 = 0.f, t1 = 0.f, t2 = 0.f, t3 = 0.f;
    for (int k = 0; k < DIM_H; k += 4) {
      t0 = fmaf(hs[k + 0], W2[(size_t)(k + 0) * DIM_H + tid], t0);
      t1 = fmaf(hs[k + 1], W2[(size_t)(k + 1) * DIM_H + tid], t1);
      t2 = fmaf(hs[k + 2], W2[(size_t)(k + 2) * DIM_H + tid], t2);
      t3 = fmaf(hs[k + 3], W2[(size_t)(k + 3) * DIM_H + tid], t3);
    }
    s2l[tid] = (t0 + t1) + (t2 + t3);
  }
  __syncthreads();
  floatx4 zero4 = {0.f, 0.f, 0.f, 0.f};
  floatx4 acc[4][3];
#pragma unroll
  for (int m = 0; m < 4; ++m)
#pragma unroll
    for (int n = 0; n < 3; ++n) acc[m][n] = zero4;
  mfma_stage_pre<6, 4>(a_lds, b, kq, lr, acc);
  float pv[16];
#pragma unroll
  for (int t = 0; t < 16; ++t) pv[t] = 0.f;
#pragma unroll
  for (int n = 0; n < 3; ++n) {
    int col = colbase + n * 16 + lr;
    float s2c = s2l[col];
    float wv = wat[col];
#pragma unroll
    for (int m = 0; m < 4; ++m)
#pragma unroll
      for (int j = 0; j < 4; ++j) {
        float xv = acc[m][n][j] + s2c;
        xv = fminf(fmaxf(xv, -10.f), 10.f);
        float t = __expf(2.f * xv);
        pv[m * 4 + j] = fmaf((t - 1.f) / (t + 1.f), wv, pv[m * 4 + j]);
      }
  }
#pragma unroll
  for (int m = 0; m < 4; ++m)
#pragma unroll
    for (int j = 0; j < 4; ++j)
      part[m * 16 + kq * 4 + j][w * 16 + lr] = pv[m * 4 + j];
  __syncthreads();
  if (tid < 64) {
    float s = 0.f;
#pragma unroll
    for (int i = 0; i < 64; ++i) s += part[tid][i];
    s = s > 0.f ? s : 0.2f * s;
    float pe = __expf(s);
    int gr = rbase + tid;
    bool valid = gr < N_NODES;
    if (valid) p[gr] = pe;
    pe = valid ? pe : 0.f;
    pe_lds[tid] = pe;
    float red = pe;
#pragma unroll
    for (int off = 32; off > 0; off >>= 1) red += __shfl_xor(red, off);
    if (tid == 0) atomicAdd(&scal[0], red);
  }
  __syncthreads();
  if (tid < DIM_H) {
    const unsigned short* al = (const unsigned short*)a_lds;
    int base = (tid >> 3) * 512 + (tid & 7);
    float s = 0.f;
    for (int it = 0; it < 64; ++it) {
      int row = (it + tid) & 63;
      s = fmaf(pe_lds[row], bf2f(al[base + row * 8]), s);
    }
    atomicAdd(&rdoutS[(blockIdx.x & (NSHADOW - 1)) * DIM_H + tid], s);
  }
}

// ---------------- alpha = p / S ----------------
__global__ void k_alpha(const float* __restrict__ p, const float* __restrict__ scal,
                        float* __restrict__ alpha) {
  int i = blockIdx.x * 256 + threadIdx.x;
  if (i < N_NODES) alpha[i] = p[i] * (1.f / scal[0]);
}

__global__ void k_logit(const float* __restrict__ rdoutS, const float* __restrict__ scal,
                        const float* __restrict__ cw, const float* __restrict__ cb,
                        float* __restrict__ out) {
  __shared__ float buf[256];
  int tid = threadIdx.x;
  float v = 0.f;
  if (tid < DIM_H) {
    float s = 0.f;
#pragma unroll
    for (int g = 0; g < NSHADOW; ++g) s += rdoutS[g * DIM_H + tid];
    v = s * cw[tid];
  }
  buf[tid] = v;
  __syncthreads();
  for (int s = 128; s > 0; s >>= 1) {
    if (tid < s) buf[tid] += buf[tid + s];
    __syncthreads();
  }
  if (tid == 0) out[0] = buf[0] * (1.f / scal[0]) + cb[0];
}

extern "C" void kernel_launch(void* const* d_in, const int* in_sizes, int n_in,
                              void* d_out, int out_size, void* d_ws, size_t ws_size,
                              hipStream_t stream) {
  const float* x      = (const float*)d_in[0];
  const int*   edge   = (const int*)d_in[1];
  const int*   seedp  = (const int*)d_in[2];
  const float* proj_w = (const float*)d_in[3];
  const float* proj_b = (const float*)d_in[4];
  const float* mlp1_w = (const float*)d_in[5];
  const float* mlp1_b = (const float*)d_in[6];
  const float* mlp2_w = (const float*)d_in[7];
  const float* mlp2_b = (const float*)d_in[8];
  const float* eps    = (const float*)d_in[9];
  const float* bn_g   = (const float*)d_in[10];
  const float* bn_b   = (const float*)d_in[11];
  const float* W1     = (const float*)d_in[12];
  const float* W2     = (const float*)d_in[13];
  const float* w_attn = (const float*)d_in[14];
  const float* cls_w  = (const float*)d_in[15];
  const float* cls_b  = (const float*)d_in[16];
  float* out = (float*)d_out;

  char* ws = (char*)d_ws;
  size_t off = 0;
  auto alloc = [&](size_t bytes) -> void* {
    void* p = ws + off;
    off = (off + bytes + 255) & ~(size_t)255;
    return p;
  };
  unsigned char*  f8a    = (unsigned char*)alloc((size_t)N_NODES * DIM_H);       // fp8 h0 / z2
  unsigned char*  f8b    = (unsigned char*)alloc((size_t)N_NODES * DIM_H);       // fp8 z1
  unsigned short* aggOut = (unsigned short*)alloc((size_t)N_NODES * DIM_H * 2);  // bf16 agg result
  unsigned short* zbf    = (unsigned short*)alloc((size_t)N_NODES * DIM_H * 2);  // bf16 z3
  float* pbuf   = (float*)alloc((size_t)N_NODES * 4);
  int* rowptr   = (int*)alloc((size_t)(N_NODES + 1) * 4);
  int* csr      = (int*)alloc((size_t)N_EDGES * 4);
  int* part     = (int*)alloc((size_t)N_NODES * 4);
  int* bsum     = (int*)alloc(64 * 4);
  // ---- zero-initialized span: cursor + stats[3 layers] + scal + rdout shadows ----
  size_t zbeg = off;
  int* cursor   = (int*)alloc((size_t)(N_NODES + 1) * 4);
  float* statsA = (float*)alloc((size_t)N_LAYERS * NSHADOW * SSTRIDE * 4);
  float* scalrd = (float*)alloc((size_t)(64 + NSHADOW * DIM_H) * 4);
  size_t zend = off;
  float* scal   = scalrd;
  float* rdoutS = scalrd + 64;
  uint4* WTall  = (uint4*)alloc((size_t)(7 * 24 * 192 + 16 * 192) * 16);

  float* statsL[N_LAYERS];
  for (int l = 0; l < N_LAYERS; ++l) statsL[l] = statsA + (size_t)l * NSHADOW * SSTRIDE;

  const uint4* B1p[N_LAYERS] = {WTall, WTall + 4608, WTall + 2 * 4608};
  const uint4* B2p[N_LAYERS] = {WTall + 3 * 4608, WTall + 4 * 4608, WTall + 5 * 4608};
  const uint4* Bap = WTall + 6 * 4608;
  const uint4* Bpp = WTall + 7 * 4608;

  const int GRID64 = (N_NODES + 63) / 64;   // 782
  const int AGG_GRID = (N_NODES + 3) / 4;

  hipMemsetAsync(ws + zbeg, 0, zend - zbeg, stream);

  // weight pack + edge histogram (merged)
  k_wtp_hist<<<WTP_BLOCKS + (N_EDGES + 255) / 256, 256, 0, stream>>>(
      mlp1_w, mlp2_w, W1, proj_w, WTall, edge, cursor);

  // CSR build
  k_scanA<<<SCAN_NBLK, 1024, 0, stream>>>(cursor, part, bsum);
  k_scanC<<<(N_NODES + 255) / 256, 256, 0, stream>>>(part, bsum, rowptr, cursor);
  k_fill<<<(N_EDGES + 255) / 256, 256, 0, stream>>>(edge, cursor, csr);

  // projection: x -> f8a (relu'd h0, fp8)
  k_proj<<<GRID64, 256, 0, stream>>>(x, Bpp, proj_b, f8a);

  // layer 0
  k_agg<false><<<AGG_GRID, 256, 0, stream>>>(f8a, rowptr, csr, statsL[0], bn_g, bn_b, eps, 0, aggOut);
  k_mlp<true><<<GRID64, 256, 0, stream>>>(aggOut, B1p[0], mlp1_b, B2p[0], mlp2_b, f8b, statsL[0]);
  // layer 1 (BN from statsL[0] + bn[0])
  k_agg<true><<<AGG_GRID, 256, 0, stream>>>(f8b, rowptr, csr, statsL[0], bn_g, bn_b, eps, 1, aggOut);
  k_mlp<true><<<GRID64, 256, 0, stream>>>(aggOut, B1p[1], mlp1_b + DIM_H, B2p[1], mlp2_b + DIM_H, f8a, statsL[1]);
  // layer 2 (BN from statsL[1] + bn[1])
  k_agg<true><<<AGG_GRID, 256, 0, stream>>>(f8a, rowptr, csr, statsL[1], bn_g + DIM_H, bn_b + DIM_H, eps, 2, aggOut);
  k_mlp<false><<<GRID64, 256, 0, stream>>>(aggOut, B1p[2], mlp1_b + 2 * DIM_H, B2p[2], mlp2_b + 2 * DIM_H, zbf, statsL[2]);

  // final: BN (statsL[2] + bn[2]) fused; attnm also does seed-proj + readout partials
  const float* g2 = bn_g + (size_t)2 * DIM_H;
  const float* b2c = bn_b + (size_t)2 * DIM_H;

  k_attnm<<<GRID64, 256, 0, stream>>>(zbf, statsL[2], g2, b2c, Bap, seedp, W2, w_attn, pbuf, scal, rdoutS);
  k_alpha<<<(N_NODES + 255) / 256, 256, 0, stream>>>(pbuf, scal, out + 1);
  k_logit<<<1, 256, 0, stream>>>(rdoutS, scal, cls_w, cls_b, out);
}